// Round 1
// 211.365 us; speedup vs baseline: 1.0025x; 1.0025x over previous
//
#include <hip/hip_runtime.h>

// EMA chunked scan + inverse-gather broadcast for DeChunkLayer (R10).
// R10 = R9 (best, 211.9 us) + ONE variable: K2 chunk<->block balance swizzle.
//
// Theory: K2's redundant replay is O(c) per block (c x 4KiB Bbuf reads via
// L1/L2 + c-long fma chain). All 512 blocks are co-resident (2/CU); dispatch
// round-robins blocks over 8 XCDs then fills CUs sequentially, so CU j of
// XCD x holds blocks {x+8j, x+8j+256} -> replay work 2c+256 spans 256..766
// chunk-iters across CUs (3x spread). Heavy CUs stream ~4 MiB Bbuf through
// L1 (~14-27 us) while light CUs idle after their ~19 us write share -> tail.
// Remap c = bid<256 ? bid : 767-bid pairs heavy with light: every CU's pair
// sums to exactly 511 iters. Bijection on [0,512) -> no semantic change.
// Predict: counters unchanged, dur -8..-15 us. Null result falsifies the
// CU-pairing model, not the straggler theory.
//
// x: (1, 16384, 1024) f32, p_selected: (16384,) f32, b: (1, 32768) i32
// out: (1, 32768, 1024) f32
// z_t = (1-p_t) z_{t-1} + p_t x_t  (p clipped to [1e-4, 1-1e-4])
// out[f] = z[t] for f in [pos[t], pos[t+1])
//
// K1: per-chunk local scan -> Bbuf/Abuf; per-segment b popcount -> bsum.
// K2: per-block redundant interchunk replay (L2/L3 Bbuf) + pos rank-select
//     + final scan + ranged broadcast writes (nontemporal).

#define DCH 1024
#define L_COMP 16384
#define L_FULL 32768
#define CHUNK 32
#define NCHUNK (L_COMP / CHUNK)   // 512
#define SEG (L_FULL / NCHUNK)     // 64 b-elements per block
#define EPSV 1e-4f

typedef float v4f __attribute__((ext_vector_type(4)));

__device__ __forceinline__ float clipp(float p) {
    p = fmaxf(p, EPSV);
    return fminf(p, 1.0f - EPSV);
}

// ---- K1: chunk-local scan (zero init) -> Bbuf[c], Abuf[c]; b segment sums
__global__ __launch_bounds__(256, 2) void chunk_kernel(
    const float* __restrict__ x, const float* __restrict__ p,
    const int* __restrict__ b,
    float* __restrict__ Bbuf, float* __restrict__ Abuf, int* __restrict__ bsum) {
    const int c = blockIdx.x;
    const int tid = threadIdx.x;
    const int lane = tid & 63;
    const int wave = tid >> 6;
    const int base = c * CHUNK;

    const v4f* x4 = reinterpret_cast<const v4f*>(x) + (size_t)base * (DCH / 4) + tid;
    v4f h = (v4f)0.f;
    float aprod = 1.0f;
    for (int ib = 0; ib < CHUNK; ib += 8) {
        v4f xv[8];
        float pv[8];
#pragma unroll
        for (int j = 0; j < 8; ++j) {
            xv[j] = x4[(ib + j) * (DCH / 4)];
            pv[j] = clipp(p[base + ib + j]); // uniform -> scalar load
        }
#pragma unroll
        for (int j = 0; j < 8; ++j) {
            float a = 1.0f - pv[j];
            h = a * h + pv[j] * xv[j];
            aprod *= a;
        }
    }
    reinterpret_cast<v4f*>(Bbuf)[c * (DCH / 4) + tid] = h;
    if (tid == 0) Abuf[c] = aprod;
    if (wave == 0) {
        int v = b[c * SEG + lane];
        int s = v;
#pragma unroll
        for (int off = 1; off < 64; off <<= 1) s += __shfl_xor(s, off, 64);
        if (lane == 0) bsum[c] = s;
    }
}

// ---- K2: bpref scan + rank-select pos + redundant interchunk + final scan/write
__global__ __launch_bounds__(256, 2) void dechunk_kernel(
    const float* __restrict__ x, const float* __restrict__ p,
    const int* __restrict__ b, float* __restrict__ out,
    const float* __restrict__ Bbuf, const float* __restrict__ Abuf,
    const int* __restrict__ bsum) {
    // R10: balance swizzle. CU pairing is (bid, bid+256) under XCD round-robin
    // dispatch; map so each pair's replay work sums to a constant 511 chunks.
    const int bid = blockIdx.x;
    const int c = (bid < NCHUNK / 2) ? bid : (767 - bid);
    const int tid = threadIdx.x;
    const int lane = tid & 63;
    const int wave = tid >> 6;
    const int base = c * CHUNK;

    __shared__ int bpref[NCHUNK + 1];
    __shared__ int spos[CHUNK + 1];
    __shared__ int wtot[4];

    // (a) block-local exclusive prefix over the 512 segment sums
    {
        int v0 = bsum[2 * tid];
        int v1 = bsum[2 * tid + 1];
        int s = v0 + v1;
        int incl = s;
#pragma unroll
        for (int off = 1; off < 64; off <<= 1) {
            int n = __shfl_up(incl, off, 64);
            if (lane >= off) incl += n;
        }
        if (lane == 63) wtot[wave] = incl;
        __syncthreads();
        int woff = 0;
        for (int w = 0; w < wave; ++w) woff += wtot[w];
        int ex = woff + incl - s; // exclusive prefix of this thread's pair
        bpref[2 * tid] = ex;
        bpref[2 * tid + 1] = ex + v0;
        if (tid == 0) bpref[NCHUNK] = L_COMP;
        __syncthreads();
    }

    // (b) rank-select this chunk's 33 pos values (threads 0..32)
    if (tid <= CHUNK) {
        int t = base + tid; // global one-rank (0-indexed)
        int posv = L_FULL;
        if (t < L_COMP) {
            int lo = 0, hi = NCHUNK;
            while (hi - lo > 1) {
                int mid = (lo + hi) >> 1;
                if (bpref[mid] <= t) lo = mid; else hi = mid;
            }
            int lr = t - bpref[lo]; // local rank within segment lo
            const int4* bseg = reinterpret_cast<const int4*>(b) + lo * (SEG / 4);
            int cnt = 0;
#pragma unroll 4
            for (int q = 0; q < SEG / 4; ++q) {
                int4 w = bseg[q];
                if (w.x) { if (cnt == lr) posv = lo * SEG + 4 * q + 0; ++cnt; }
                if (w.y) { if (cnt == lr) posv = lo * SEG + 4 * q + 1; ++cnt; }
                if (w.z) { if (cnt == lr) posv = lo * SEG + 4 * q + 2; ++cnt; }
                if (w.w) { if (cnt == lr) posv = lo * SEG + 4 * q + 3; ++cnt; }
            }
        }
        spos[tid] = posv;
    }

    // (c) redundant interchunk replay: h = state before chunk c (4 channels/thread)
    v4f h = (v4f)0.f;
    {
        const v4f* B4 = reinterpret_cast<const v4f*>(Bbuf) + tid;
        int k = 0;
        for (; k + 16 <= c; k += 16) {
            v4f bv[16];
            float av[16];
#pragma unroll
            for (int j = 0; j < 16; ++j) {
                bv[j] = B4[(k + j) * (DCH / 4)];
                av[j] = Abuf[k + j]; // uniform -> scalar load
            }
#pragma unroll
            for (int j = 0; j < 16; ++j)
                h = av[j] * h + bv[j];
        }
        for (; k < c; ++k) {
            v4f bv = B4[k * (DCH / 4)];
            h = Abuf[k] * h + bv;
        }
    }
    __syncthreads();

    // (d) final scan of chunk c with true init; ranged broadcast writes (NT)
    {
        const v4f* x4 = reinterpret_cast<const v4f*>(x) + (size_t)base * (DCH / 4) + tid;
        v4f* out4 = reinterpret_cast<v4f*>(out) + tid;
        int f0 = spos[0];
        for (int ib = 0; ib < CHUNK; ib += 8) {
            v4f xv[8];
            float pv[8];
            int fe[8];
#pragma unroll
            for (int j = 0; j < 8; ++j) {
                xv[j] = x4[(ib + j) * (DCH / 4)];   // cached: L3-warm x
                pv[j] = clipp(p[base + ib + j]);    // uniform -> scalar
                fe[j] = spos[ib + j + 1];           // LDS
            }
#pragma unroll
            for (int j = 0; j < 8; ++j) {
                float a = 1.0f - pv[j];
                h = a * h + pv[j] * xv[j];
                for (int f = f0; f < fe[j]; ++f) {
                    __builtin_nontemporal_store(h, &out4[(size_t)f * (DCH / 4)]);
                }
                f0 = fe[j];
            }
        }
    }
}

extern "C" void kernel_launch(void* const* d_in, const int* in_sizes, int n_in,
                              void* d_out, int out_size, void* d_ws, size_t ws_size,
                              hipStream_t stream) {
    const float* x = (const float*)d_in[0];
    const float* p = (const float*)d_in[1];
    const int* b = (const int*)d_in[2];
    float* out = (float*)d_out;

    char* ws = (char*)d_ws;
    float* Abuf = (float*)ws;                  // NCHUNK floats (2 KiB)
    int* bsum = (int*)(ws + 4096);             // NCHUNK ints (2 KiB)
    float* Bbuf = (float*)(ws + 8192);         // NCHUNK*DCH floats (2 MiB), 16B aligned

    chunk_kernel<<<NCHUNK, 256, 0, stream>>>(x, p, b, Bbuf, Abuf, bsum);
    dechunk_kernel<<<NCHUNK, 256, 0, stream>>>(x, p, b, out, Bbuf, Abuf, bsum);
}

// Round 2
// 198.622 us; speedup vs baseline: 1.0668x; 1.0642x over previous
//
#include <hip/hip_runtime.h>

// EMA chunked scan + inverse-gather broadcast for DeChunkLayer (R11).
// R11 = R9 (best, 211.9 us; R10 swizzle was null and is reverted) + ONE
// variable: numerically-windowed interchunk replay.
//
// Theory: replay terms from chunk k into state-before-chunk-c carry weight
// prod A[j] (j=k+1..c-1) = 2^(LA[c]-LA[k+1]). With bench p ~ U(0,1),
// per-chunk log2 A ~ -46, so only k=c-1 exceeds 2^-40 (absmax tol is 2^-6;
// dropped terms are < 2^-34 of it). Replay currently streams c x 4KiB of
// Bbuf per block (~511 MiB aggregate L1/L2 traffic + dependent-FMA latency)
// to add zeros. Fix: float prefix scan of clamp(log2 A, -1000) alongside
// the existing bpref int scan, binary-search the earliest chunk with weight
// >= 2^-40, start replay there. Data-adaptive: worst case (A~1) degrades to
// the current full replay, so this is NOT a distribution gamble.
// Predict: FETCH/WRITE unchanged (replay was L2-resident); dur -10..-20 us.
// Null => replay fully hidden; gap is store-path/occupancy -> D-split next.
//
// x: (1, 16384, 1024) f32, p_selected: (16384,) f32, b: (1, 32768) i32
// out: (1, 32768, 1024) f32
// z_t = (1-p_t) z_{t-1} + p_t x_t  (p clipped to [1e-4, 1-1e-4])
// out[f] = z[t] for f in [pos[t], pos[t+1])
//
// K1: per-chunk local scan -> Bbuf/Abuf; per-segment b popcount -> bsum.
// K2: per-block windowed interchunk replay (L2 Bbuf) + pos rank-select
//     + final scan + ranged broadcast writes (nontemporal).

#define DCH 1024
#define L_COMP 16384
#define L_FULL 32768
#define CHUNK 32
#define NCHUNK (L_COMP / CHUNK)   // 512
#define SEG (L_FULL / NCHUNK)     // 64 b-elements per block
#define EPSV 1e-4f
#define LOG2_THRESH 40.0f         // drop replay terms with weight < 2^-40

typedef float v4f __attribute__((ext_vector_type(4)));

__device__ __forceinline__ float clipp(float p) {
    p = fmaxf(p, EPSV);
    return fminf(p, 1.0f - EPSV);
}

// ---- K1: chunk-local scan (zero init) -> Bbuf[c], Abuf[c]; b segment sums
__global__ __launch_bounds__(256, 2) void chunk_kernel(
    const float* __restrict__ x, const float* __restrict__ p,
    const int* __restrict__ b,
    float* __restrict__ Bbuf, float* __restrict__ Abuf, int* __restrict__ bsum) {
    const int c = blockIdx.x;
    const int tid = threadIdx.x;
    const int lane = tid & 63;
    const int wave = tid >> 6;
    const int base = c * CHUNK;

    const v4f* x4 = reinterpret_cast<const v4f*>(x) + (size_t)base * (DCH / 4) + tid;
    v4f h = (v4f)0.f;
    float aprod = 1.0f;
    for (int ib = 0; ib < CHUNK; ib += 8) {
        v4f xv[8];
        float pv[8];
#pragma unroll
        for (int j = 0; j < 8; ++j) {
            xv[j] = x4[(ib + j) * (DCH / 4)];
            pv[j] = clipp(p[base + ib + j]); // uniform -> scalar load
        }
#pragma unroll
        for (int j = 0; j < 8; ++j) {
            float a = 1.0f - pv[j];
            h = a * h + pv[j] * xv[j];
            aprod *= a;
        }
    }
    reinterpret_cast<v4f*>(Bbuf)[c * (DCH / 4) + tid] = h;
    if (tid == 0) Abuf[c] = aprod;
    if (wave == 0) {
        int v = b[c * SEG + lane];
        int s = v;
#pragma unroll
        for (int off = 1; off < 64; off <<= 1) s += __shfl_xor(s, off, 64);
        if (lane == 0) bsum[c] = s;
    }
}

// ---- K2: bpref+log2A scans + rank-select pos + windowed replay + scan/write
__global__ __launch_bounds__(256, 2) void dechunk_kernel(
    const float* __restrict__ x, const float* __restrict__ p,
    const int* __restrict__ b, float* __restrict__ out,
    const float* __restrict__ Bbuf, const float* __restrict__ Abuf,
    const int* __restrict__ bsum) {
    const int c = blockIdx.x;
    const int tid = threadIdx.x;
    const int lane = tid & 63;
    const int wave = tid >> 6;
    const int base = c * CHUNK;

    __shared__ int bpref[NCHUNK + 1];
    __shared__ float lapref[NCHUNK + 1];  // exclusive prefix of log2(A)
    __shared__ int spos[CHUNK + 1];
    __shared__ int wtot[4];
    __shared__ float wtotf[4];

    // (a) block-local exclusive prefixes over the 512 segment sums (int)
    //     and the 512 log2-decay values (float), fused in one butterfly.
    {
        int v0 = bsum[2 * tid];
        int v1 = bsum[2 * tid + 1];
        // clamp at -1000: A==0 (underflow) must not produce -inf - -inf = NaN
        // in the exclusive-scan subtraction; -1000/chunk >> LOG2_THRESH keeps
        // the windowing semantics exact (older terms dropped).
        float l0 = fmaxf(log2f(Abuf[2 * tid]), -1000.0f);
        float l1 = fmaxf(log2f(Abuf[2 * tid + 1]), -1000.0f);
        int s = v0 + v1;
        float ls = l0 + l1;
        int incl = s;
        float lincl = ls;
#pragma unroll
        for (int off = 1; off < 64; off <<= 1) {
            int n = __shfl_up(incl, off, 64);
            float lf = __shfl_up(lincl, off, 64);
            if (lane >= off) { incl += n; lincl += lf; }
        }
        if (lane == 63) { wtot[wave] = incl; wtotf[wave] = lincl; }
        __syncthreads();
        int woff = 0;
        float lwoff = 0.0f;
        for (int w = 0; w < wave; ++w) { woff += wtot[w]; lwoff += wtotf[w]; }
        int ex = woff + incl - s;        // exclusive prefix of this pair
        float lex = lwoff + lincl - ls;
        bpref[2 * tid] = ex;
        bpref[2 * tid + 1] = ex + v0;
        lapref[2 * tid] = lex;
        lapref[2 * tid + 1] = lex + l0;
        if (tid == 0) bpref[NCHUNK] = L_COMP;
        __syncthreads();
    }

    // (b) rank-select this chunk's 33 pos values (threads 0..32)
    if (tid <= CHUNK) {
        int t = base + tid; // global one-rank (0-indexed)
        int posv = L_FULL;
        if (t < L_COMP) {
            int lo = 0, hi = NCHUNK;
            while (hi - lo > 1) {
                int mid = (lo + hi) >> 1;
                if (bpref[mid] <= t) lo = mid; else hi = mid;
            }
            int lr = t - bpref[lo]; // local rank within segment lo
            const int4* bseg = reinterpret_cast<const int4*>(b) + lo * (SEG / 4);
            int cnt = 0;
#pragma unroll 4
            for (int q = 0; q < SEG / 4; ++q) {
                int4 w = bseg[q];
                if (w.x) { if (cnt == lr) posv = lo * SEG + 4 * q + 0; ++cnt; }
                if (w.y) { if (cnt == lr) posv = lo * SEG + 4 * q + 1; ++cnt; }
                if (w.z) { if (cnt == lr) posv = lo * SEG + 4 * q + 2; ++cnt; }
                if (w.w) { if (cnt == lr) posv = lo * SEG + 4 * q + 3; ++cnt; }
            }
        }
        spos[tid] = posv;
    }

    // (c) windowed interchunk replay: h = state before chunk c.
    //     Weight of chunk k is 2^(lapref[c] - lapref[k+1]); keep only terms
    //     >= 2^-LOG2_THRESH. lapref is non-increasing -> kept set is a
    //     suffix [kstart, c-1]; binary search its start. Uniform per block.
    v4f h = (v4f)0.f;
    {
        const float lim = lapref[c] + LOG2_THRESH;
        int kstart = 0;
        if (lapref[0] > lim) {
            int lo = 0, hi = c; // lapref[lo] > lim, lapref[hi] <= lim
            while (hi - lo > 1) {
                int mid = (lo + hi) >> 1;
                if (lapref[mid] > lim) lo = mid; else hi = mid;
            }
            kstart = hi - 1; // include one boundary term (weight may be tiny)
        }
        const v4f* B4 = reinterpret_cast<const v4f*>(Bbuf) + tid;
        int k = kstart;
        for (; k + 16 <= c; k += 16) {
            v4f bv[16];
            float av[16];
#pragma unroll
            for (int j = 0; j < 16; ++j) {
                bv[j] = B4[(k + j) * (DCH / 4)];
                av[j] = Abuf[k + j]; // uniform -> scalar load
            }
#pragma unroll
            for (int j = 0; j < 16; ++j)
                h = av[j] * h + bv[j];
        }
        for (; k < c; ++k) {
            v4f bv = B4[k * (DCH / 4)];
            h = Abuf[k] * h + bv;
        }
    }
    __syncthreads();

    // (d) final scan of chunk c with true init; ranged broadcast writes (NT)
    {
        const v4f* x4 = reinterpret_cast<const v4f*>(x) + (size_t)base * (DCH / 4) + tid;
        v4f* out4 = reinterpret_cast<v4f*>(out) + tid;
        int f0 = spos[0];
        for (int ib = 0; ib < CHUNK; ib += 8) {
            v4f xv[8];
            float pv[8];
            int fe[8];
#pragma unroll
            for (int j = 0; j < 8; ++j) {
                xv[j] = x4[(ib + j) * (DCH / 4)];   // cached: L3-warm x
                pv[j] = clipp(p[base + ib + j]);    // uniform -> scalar
                fe[j] = spos[ib + j + 1];           // LDS
            }
#pragma unroll
            for (int j = 0; j < 8; ++j) {
                float a = 1.0f - pv[j];
                h = a * h + pv[j] * xv[j];
                for (int f = f0; f < fe[j]; ++f) {
                    __builtin_nontemporal_store(h, &out4[(size_t)f * (DCH / 4)]);
                }
                f0 = fe[j];
            }
        }
    }
}

extern "C" void kernel_launch(void* const* d_in, const int* in_sizes, int n_in,
                              void* d_out, int out_size, void* d_ws, size_t ws_size,
                              hipStream_t stream) {
    const float* x = (const float*)d_in[0];
    const float* p = (const float*)d_in[1];
    const int* b = (const int*)d_in[2];
    float* out = (float*)d_out;

    char* ws = (char*)d_ws;
    float* Abuf = (float*)ws;                  // NCHUNK floats (2 KiB)
    int* bsum = (int*)(ws + 4096);             // NCHUNK ints (2 KiB)
    float* Bbuf = (float*)(ws + 8192);         // NCHUNK*DCH floats (2 MiB), 16B aligned

    chunk_kernel<<<NCHUNK, 256, 0, stream>>>(x, p, b, Bbuf, Abuf, bsum);
    dechunk_kernel<<<NCHUNK, 256, 0, stream>>>(x, p, b, out, Bbuf, Abuf, bsum);
}